// Round 8
// baseline (179.254 us; speedup 1.0000x reference)
//
#include <hip/hip_runtime.h>
#include <hip/hip_bf16.h>

// B=2, T=2048, D=1024, H=16, hd=64
#define T_SEQ 2048
#define D_MODEL 1024
#define BT 4096
#define QKV_N 3072

typedef __attribute__((ext_vector_type(8))) short bf16x8;
typedef __attribute__((ext_vector_type(4))) short bf16x4;
typedef __attribute__((ext_vector_type(4))) float f32x4;

typedef unsigned int __attribute__((address_space(1))) as1_uint;
typedef unsigned int __attribute__((address_space(3))) as3_uint;

__device__ __forceinline__ unsigned short f2bf(float f) {
    unsigned u = __builtin_bit_cast(unsigned, f);
    u += 0x7fffu + ((u >> 16) & 1u);   // round-to-nearest-even
    return (unsigned short)(u >> 16);
}
__device__ __forceinline__ float bf2f(unsigned short h) {
    unsigned u = ((unsigned)h) << 16;
    return __builtin_bit_cast(float, u);
}
__device__ __forceinline__ void gload_lds16(const void* g, void* l) {
    __builtin_amdgcn_global_load_lds((const as1_uint*)g, (as3_uint*)l, 16, 0, 0);
}
__device__ __forceinline__ unsigned cvtpk_bf16(float lo, float hi) {
    unsigned r;
    asm("v_cvt_pk_bf16_f32 %0, %1, %2" : "=v"(r) : "v"(lo), "v"(hi));
    return r;
}

// ---------------- fp32 -> bf16 convert, all three tensors in one launch ------
__global__ __launch_bounds__(256) void cvt_bf16_3(const float* __restrict__ s0, unsigned short* __restrict__ d0, int n0,
                                                  const float* __restrict__ s1, unsigned short* __restrict__ d1, int n1,
                                                  const float* __restrict__ s2, unsigned short* __restrict__ d2, int n2) {
    int i = blockIdx.x * 256 + threadIdx.x;   // 8-element units
    const float* s; unsigned short* d;
    if (i < n0) { s = s0; d = d0; }
    else if (i < n0 + n1) { i -= n0; s = s1; d = d1; }
    else if (i < n0 + n1 + n2) { i -= n0 + n1; s = s2; d = d2; }
    else return;
    const float4* sp = (const float4*)s + (size_t)i * 2;
    const float4 a = sp[0], b = sp[1];
    uint4 o;
    o.x = (unsigned)f2bf(a.x) | ((unsigned)f2bf(a.y) << 16);
    o.y = (unsigned)f2bf(a.z) | ((unsigned)f2bf(a.w) << 16);
    o.z = (unsigned)f2bf(b.x) | ((unsigned)f2bf(b.y) << 16);
    o.w = (unsigned)f2bf(b.z) | ((unsigned)f2bf(b.w) << 16);
    ((uint4*)d)[i] = o;
}

// ---------------- MFMA GEMM: C[M,N] = A[M,K] @ B[N,K]^T (bf16 in, fp32 acc) ----
// m97 structure: 128x128 tile, BK=64, 4 waves, global_load_lds width 16,
// slot-XOR swizzle keyed on row&7. 1D grid, XCD-chunked decode.
// MODE 0: fp32 C write.  MODE 2: fused QKV epilogue — q/k waves L2-normalize
// their head (64 cols = one wave) and write bf16 to qb/kb [bh][t][64];
// v waves write bf16 to vrow [4096][1024].
template<int MODE>
__global__ __launch_bounds__(256) void gemm_bt_mfma(const unsigned short* __restrict__ A,
                                                    const unsigned short* __restrict__ B,
                                                    void* __restrict__ Cout,
                                                    unsigned short* __restrict__ qbp,
                                                    unsigned short* __restrict__ kbp,
                                                    int M, int N, int K) {
    __shared__ unsigned short As[128 * 64];
    __shared__ unsigned short Bs[128 * 64];
    const int tid = threadIdx.x;
    const int w = tid >> 6;
    const int l = tid & 63;
    const int l15 = l & 15, l4 = l >> 4;

    // XCD-chunked: each XCD gets a contiguous run of n-strips x 32 m-tiles
    const int nblocks = (M / 128) * (N / 128);
    const int cpx = nblocks >> 3;
    const int id2 = (blockIdx.x & 7) * cpx + (blockIdx.x >> 3);
    const int bm = (id2 & 31) * 128;
    const int bn = (id2 >> 5) * 128;

    const int wm = (w >> 1) * 64, wn = (w & 1) * 64;

    const f32x4 z = {0.f, 0.f, 0.f, 0.f};
    f32x4 acc[4][4];
#pragma unroll
    for (int m = 0; m < 4; ++m)
#pragma unroll
        for (int n = 0; n < 4; ++n) acc[m][n] = z;

    const int lrow = l >> 3;
    const int lslot = (l & 7) ^ (lrow & 7);   // pre-swizzled global source slot

    for (int k0 = 0; k0 < K; k0 += 64) {
#pragma unroll
        for (int i = 0; i < 4; ++i) {
            const int row = w * 32 + i * 8 + lrow;
            gload_lds16(A + (size_t)(bm + row) * K + k0 + lslot * 8, As + (w * 4 + i) * 512);
            gload_lds16(B + (size_t)(bn + row) * K + k0 + lslot * 8, Bs + (w * 4 + i) * 512);
        }
        __syncthreads();
        bf16x8 af[4][2], bfr[4][2];
#pragma unroll
        for (int m = 0; m < 4; ++m) {
            const int row = wm + m * 16 + l15;
            af[m][0] = *(const bf16x8*)(As + row * 64 + ((l4 ^ (row & 7)) * 8));
            af[m][1] = *(const bf16x8*)(As + row * 64 + (((4 + l4) ^ (row & 7)) * 8));
        }
#pragma unroll
        for (int n = 0; n < 4; ++n) {
            const int row = wn + n * 16 + l15;
            bfr[n][0] = *(const bf16x8*)(Bs + row * 64 + ((l4 ^ (row & 7)) * 8));
            bfr[n][1] = *(const bf16x8*)(Bs + row * 64 + (((4 + l4) ^ (row & 7)) * 8));
        }
#pragma unroll
        for (int m = 0; m < 4; ++m)
#pragma unroll
            for (int n = 0; n < 4; ++n) {
                acc[m][n] = __builtin_amdgcn_mfma_f32_16x16x32_bf16(af[m][0], bfr[n][0], acc[m][n], 0, 0, 0);
                acc[m][n] = __builtin_amdgcn_mfma_f32_16x16x32_bf16(af[m][1], bfr[n][1], acc[m][n], 0, 0, 0);
            }
        __syncthreads();
    }

    if (MODE == 0) {
#pragma unroll
        for (int m = 0; m < 4; ++m)
#pragma unroll
            for (int n = 0; n < 4; ++n)
#pragma unroll
                for (int r = 0; r < 4; ++r) {
                    const int row = bm + wm + m * 16 + l4 * 4 + r;
                    const int col = bn + wn + n * 16 + l15;
                    ((float*)Cout)[(size_t)row * N + col] = acc[m][n][r];
                }
    } else {
        // fused QKV epilogue. Wave's 64 cols = exactly one head of q, k or v.
        const int gcol0 = bn + wn;
        const int part = gcol0 >> 10;        // 0=q 1=k 2=v (wave-uniform)
        const int h = (gcol0 >> 6) & 15;
        if (part < 2) {
            unsigned short* dst = part ? kbp : qbp;
#pragma unroll
            for (int m = 0; m < 4; ++m)
#pragma unroll
                for (int r = 0; r < 4; ++r) {
                    float ss = 0.f;
#pragma unroll
                    for (int n = 0; n < 4; ++n) ss = fmaf(acc[m][n][r], acc[m][n][r], ss);
                    ss += __shfl_xor(ss, 1);
                    ss += __shfl_xor(ss, 2);
                    ss += __shfl_xor(ss, 4);
                    ss += __shfl_xor(ss, 8);
                    const float sc = 1.0f / fmaxf(sqrtf(ss), 1e-12f);
                    const int row = bm + wm + m * 16 + l4 * 4 + r;
                    const int bh2 = (row >> 11) * 16 + h;
                    unsigned short* pdst = dst + ((size_t)bh2 * T_SEQ + (row & 2047)) * 64 + l15;
#pragma unroll
                    for (int n = 0; n < 4; ++n) pdst[n * 16] = f2bf(acc[m][n][r] * sc);
                }
        } else {
            unsigned short* vrow = (unsigned short*)Cout;    // [4096][1024]
            const int vcol0 = gcol0 - 2048;
#pragma unroll
            for (int m = 0; m < 4; ++m)
#pragma unroll
                for (int n = 0; n < 4; ++n)
#pragma unroll
                    for (int r = 0; r < 4; ++r) {
                        const int row = bm + wm + m * 16 + l4 * 4 + r;
                        vrow[(size_t)row * D_MODEL + vcol0 + n * 16 + l15] = f2bf(acc[m][n][r]);
                    }
        }
    }
}

// ---------------- V relayout: vrow [b][t][h*64+d] -> vbT [b][h][d][t''] ------
// Within each 64-aligned t-group, stores position s'' where:
//   s' = perm(t&63):  s'=[t5 t3 t2 t4 t1 t0]   (so PV A-frag sigma matches)
//   s''= slot-swizzle: 8-short slot index (s'>>3) ^= (d&7)
// This makes attn's PV B-fragment a single b128 read mirroring the K reads.
__global__ __launch_bounds__(256) void v_cvt_T(const unsigned short* __restrict__ vrow,
                                               unsigned short* __restrict__ vbT) {
    __shared__ unsigned short tile[64][72];  // [d][t]
    const int bh = blockIdx.y;
    const int b = bh >> 4, h = bh & 15;
    const int t0 = blockIdx.x * 64;
    const int r = threadIdx.x >> 2;          // t within tile
    const int c = (threadIdx.x & 3) * 16;    // d chunk
    const unsigned short* src = vrow + (size_t)(b * T_SEQ + t0 + r) * D_MODEL + h * 64 + c;
    uint4 v0 = *(const uint4*)(src);
    uint4 v1 = *(const uint4*)(src + 8);
    unsigned short tmp[16];
    *(uint4*)tmp = v0;
    *(uint4*)(tmp + 8) = v1;
#pragma unroll
    for (int j = 0; j < 16; ++j) tile[c + j][r] = tmp[j];
    __syncthreads();
    const int d = threadIdx.x >> 2;
    const int tc = (threadIdx.x & 3) * 16;   // t chunk base (0,16,32,48)
    const int t5 = tc >> 5, t4 = (tc >> 4) & 1;
    unsigned short* dstrow = vbT + ((size_t)bh * 64 + d) * T_SEQ + t0;
    const int dp = d & 7;
#pragma unroll
    for (int q = 0; q < 4; ++q) {            // j = q*4 + i, i=0..3
        unsigned short tmp2[4];
#pragma unroll
        for (int i = 0; i < 4; ++i) tmp2[i] = tile[d][tc + q * 4 + i];
        const int slot = (t5 * 4 + q) ^ dp;
        *(uint2*)(dstrow + slot * 8 + t4 * 4) = *(uint2*)tmp2;
    }
}

// ---------------- Causal YAT attention, MFMA, pipelined, swapped-QK ----------
// 4 waves/block, q-tile 64 (wave owns 16 rows), key tiles of 64, K/V^T
// double-buffered in LDS via global_load_lds + counted vmcnt. Swapped QK^T
// (mfma(K,Q)) + slot-permutation sigma on both PV operands: no S LDS
// round-trip, no cross-lane ops. V layout is pre-permuted+swizzled (v_cvt_T)
// so PV B-frags are single b128 reads mirroring the K reads.
// Block decode: complement-balanced so any co-resident quad (consecutive-4
// OR stride-32 blockIdx sets) has constant total work.
#define AT_TS 64

__global__ __launch_bounds__(256, 4) void attn_mfma(const unsigned short* __restrict__ qb,
                                                    const unsigned short* __restrict__ kb,
                                                    const unsigned short* __restrict__ vbT,
                                                    unsigned short* __restrict__ attnb) {
    __shared__ unsigned short Ks[2][64 * 64];   // [buf][s-row][8 slots of 8], slot-swizzled
    __shared__ unsigned short Vs[2][64 * 64];   // [buf][d-row][8 slots], pre-swizzled in vbT

    const int tid = threadIdx.x;
    const int w = tid >> 6;
    const int l = tid & 63;
    const int l15 = l & 15, l4 = l >> 4;

    // complement-balanced decode: head=(w5,w0), v=[w6 w4 w3 w2 w1],
    // t0i = (w5^w0) ? 31-v : v  -> co-resident quads sum to 66 tiles always
    const int id = blockIdx.x;               // 0..1023
    const int xcd = id & 7;
    const int within = id >> 3;              // 0..127
    const int hl = (((within >> 5) & 1) << 1) | (within & 1);
    const int vv = (((within >> 6) & 1) << 4) | (((within >> 4) & 1) << 3) |
                   (((within >> 3) & 1) << 2) | (((within >> 2) & 1) << 1) |
                   ((within >> 1) & 1);
    const int pfl = ((within >> 5) & 1) ^ (within & 1);
    const int bh = xcd * 4 + hl;
    const int t0i = pfl ? 31 - vv : vv;
    const int t0 = t0i * 64;

    const size_t hb = (size_t)bh * T_SEQ * 64;

    // ---- staging pointers (advanced incrementally per step) ----
    const int lrow = l >> 3;
    const int lslot = (l & 7) ^ (lrow & 7);   // K: bake swizzle at stage
    const unsigned short* kgp[2];
    const unsigned short* vgp[2];
    unsigned short* kdst[2];
    unsigned short* vdst[2];
#pragma unroll
    for (int c = 0; c < 2; ++c) {
        const int row = w * 16 + c * 8 + lrow;
        kgp[c] = kb + hb + (size_t)row * 64 + lslot * 8;
        vgp[c] = vbT + hb + (size_t)row * T_SEQ + (l & 7) * 8;  // V: linear (pre-baked)
        kdst[c] = &Ks[0][(w * 2 + c) * 512];
        vdst[c] = &Vs[0][(w * 2 + c) * 512];
    }

    // ---- hoisted LDS read bases (st/df/sf-invariant) ----
    const int p = l15 & 7;                    // (row&7) for all frag rows
    const unsigned short* kfp0 = &Ks[0][0] + l15 * 64 + ((l4 ^ p) * 8);
    const unsigned short* kfp1 = &Ks[0][0] + l15 * 64 + (((4 + l4) ^ p) * 8);
    const unsigned short* vfp0 = &Vs[0][0] + l15 * 64 + ((l4 ^ p) * 8);
    const unsigned short* vfp1 = &Vs[0][0] + l15 * 64 + (((4 + l4) ^ p) * 8);

    // Q B-fragment: col = q = l15 (wave rows t0 + w*16 + l15), k = d
    bf16x8 qf0, qf1;
    {
        const unsigned short* qp = qb + hb + (size_t)(t0 + w * 16 + l15) * 64 + l4 * 8;
        qf0 = *(const bf16x8*)(qp);
        qf1 = *(const bf16x8*)(qp + 32);
    }

    const f32x4 z = {0.f, 0.f, 0.f, 0.f};
    f32x4 acc[4];
#pragma unroll
    for (int i = 0; i < 4; ++i) acc[i] = z;
    float accd = 0.f;                        // denominator partial for q = l15

    const int wrow0 = t0 + w * 16;
    const int tq = wrow0 + l15;              // this lane's q row

    // prologue: stage tile 0 into buf 0 (4 loads per thread)
#pragma unroll
    for (int c = 0; c < 2; ++c) {
        gload_lds16(kgp[c], kdst[c]);
        gload_lds16(vgp[c], vdst[c]);
    }

    auto compute_tile = [&](int roff, int s0, bool mask) {
        // ---- swapped QK^T: sC[sf] rows = s (sf*16 + l4*4 + r), col = q = l15 ----
        const unsigned short* kc0 = kfp0 + roff;
        const unsigned short* kc1 = kfp1 + roff;
        f32x4 sC[4];
        __builtin_amdgcn_s_setprio(1);
#pragma unroll
        for (int sf = 0; sf < 4; ++sf) {
            bf16x8 kf0 = *(const bf16x8*)(kc0 + sf * 1024);
            bf16x8 kf1 = *(const bf16x8*)(kc1 + sf * 1024);
            f32x4 c = z;
            c = __builtin_amdgcn_mfma_f32_16x16x32_bf16(kf0, qf0, c, 0, 0, 0);
            c = __builtin_amdgcn_mfma_f32_16x16x32_bf16(kf1, qf1, c, 0, 0, 0);
            sC[sf] = c;
        }
        __builtin_amdgcn_s_setprio(0);
        // ---- YAT transform + (optional) causal mask + lane-local row-sum ----
        float part_ = 0.f;
#pragma unroll
        for (int sf = 0; sf < 4; ++sf)
#pragma unroll
            for (int r = 0; r < 4; ++r) {
                const float xd = sC[sf][r];
                const float den = __builtin_fmaf(-2.0f, xd, 2.01f);
                float Kv = xd * xd * __builtin_amdgcn_rcpf(den);
                if (mask) {
                    const int s = s0 + sf * 16 + l4 * 4 + r;
                    if (s > tq) Kv = 0.f;
                }
                part_ += Kv;
                sC[sf][r] = Kv;
            }
        accd += part_;
        // ---- pack A-frags: slot (l4,j) <- S[q][(j>>2)*16 + l4*4 + (j&3)] ----
        uint4 p0, p1;
        p0.x = cvtpk_bf16(sC[0][0], sC[0][1]);
        p0.y = cvtpk_bf16(sC[0][2], sC[0][3]);
        p0.z = cvtpk_bf16(sC[1][0], sC[1][1]);
        p0.w = cvtpk_bf16(sC[1][2], sC[1][3]);
        p1.x = cvtpk_bf16(sC[2][0], sC[2][1]);
        p1.y = cvtpk_bf16(sC[2][2], sC[2][3]);
        p1.z = cvtpk_bf16(sC[3][0], sC[3][1]);
        p1.w = cvtpk_bf16(sC[3][2], sC[3][3]);
        const bf16x8 a0 = __builtin_bit_cast(bf16x8, p0);
        const bf16x8 a1 = __builtin_bit_cast(bf16x8, p1);
        // ---- PV: B-frags are single b128 reads (layout pre-permuted) ----
        const unsigned short* vc0 = vfp0 + roff;
        const unsigned short* vc1 = vfp1 + roff;
        __builtin_amdgcn_s_setprio(1);
#pragma unroll
        for (int df = 0; df < 4; ++df) {
            const bf16x8 B0 = *(const bf16x8*)(vc0 + df * 1024);
            const bf16x8 B1 = *(const bf16x8*)(vc1 + df * 1024);
            acc[df] = __builtin_amdgcn_mfma_f32_16x16x32_bf16(a0, B0, acc[df], 0, 0, 0);
            acc[df] = __builtin_amdgcn_mfma_f32_16x16x32_bf16(a1, B1, acc[df], 0, 0, 0);
        }
        __builtin_amdgcn_s_setprio(0);
    };

    // interior steps: prefetch next tile, no causal mask
    for (int st = 0; st < t0i; ++st) {
        const int dsto = ((st & 1) ^ 1) * 4096;
#pragma unroll
        for (int c = 0; c < 2; ++c) {
            kgp[c] += 4096;   // next 64 s-rows
            vgp[c] += 64;     // next 64 t-cols
            gload_lds16(kgp[c], kdst[c] + dsto);
            gload_lds16(vgp[c], vdst[c] + dsto);
        }
        asm volatile("s_waitcnt vmcnt(4)" ::: "memory");
        __builtin_amdgcn_sched_barrier(0);
        __builtin_amdgcn_s_barrier();
        compute_tile((st & 1) * 4096, st * AT_TS, false);
        __builtin_amdgcn_sched_barrier(0);
        __builtin_amdgcn_s_barrier();
    }
    // final (diagonal) step: mask, no prefetch, no trailing barrier
    {
        asm volatile("s_waitcnt vmcnt(0)" ::: "memory");
        __builtin_amdgcn_sched_barrier(0);
        __builtin_amdgcn_s_barrier();
        compute_tile((t0i & 1) * 4096, t0i * AT_TS, true);
    }

    // denominator: reduce across l4 groups (disjoint s ranges), then fetch per-row
    accd += __shfl_xor(accd, 16);
    accd += __shfl_xor(accd, 32);

    const int b = bh >> 4, h = bh & 15;
#pragma unroll
    for (int r = 0; r < 4; ++r) {
        const float den = __shfl(accd, l4 * 4 + r) + 1e-6f;
#pragma unroll
        for (int df = 0; df < 4; ++df) {
            const int t = wrow0 + l4 * 4 + r;
            const float o = acc[df][r] / den;
            attnb[((size_t)b * T_SEQ + t) * D_MODEL + h * 64 + df * 16 + l15] = f2bf(o);
        }
    }
}

extern "C" void kernel_launch(void* const* d_in, const int* in_sizes, int n_in,
                              void* d_out, int out_size, void* d_ws, size_t ws_size,
                              hipStream_t stream) {
    const float* x    = (const float*)d_in[0];   // [2,2048,1024]
    const float* Wqkv = (const float*)d_in[1];   // [3072,1024]
    const float* Wout = (const float*)d_in[2];   // [1024,1024]
    float* out = (float*)d_out;                  // [2,2048,1024] fp32

    // Workspace overlay (58 MB):
    //  [0,8):    xb          [8,16):  wqkvb (6 used)
    //  [16,24):  vrow        [24,32): vbT
    //  [32,34):  woutb
    //  [34,42):  qb          [42,50): kb        [50,58): attnb
    char* ws = (char*)d_ws;
    unsigned short* xb    = (unsigned short*)(ws);
    unsigned short* wqkvb = (unsigned short*)(ws + (size_t)8 * 1024 * 1024);
    unsigned short* vrow  = (unsigned short*)(ws + (size_t)16 * 1024 * 1024);
    unsigned short* vbT   = (unsigned short*)(ws + (size_t)24 * 1024 * 1024);
    unsigned short* woutb = (unsigned short*)(ws + (size_t)32 * 1024 * 1024);
    unsigned short* qbp   = (unsigned short*)(ws + (size_t)34 * 1024 * 1024);
    unsigned short* kbp   = (unsigned short*)(ws + (size_t)42 * 1024 * 1024);
    unsigned short* attnb = (unsigned short*)(ws + (size_t)50 * 1024 * 1024);

    cvt_bf16_3<<<4096, 256, 0, stream>>>(x, xb, BT * D_MODEL / 8,
                                         Wqkv, wqkvb, QKV_N * D_MODEL / 8,
                                         Wout, woutb, D_MODEL * D_MODEL / 8);

    // QKV GEMM with fused L2-norm (q,k -> qbp/kbp) and v -> vrow
    gemm_bt_mfma<2><<<(QKV_N / 128) * (BT / 128), 256, 0, stream>>>(
        xb, wqkvb, vrow, qbp, kbp, BT, QKV_N, D_MODEL);

    v_cvt_T<<<dim3(T_SEQ / 64, 32), 256, 0, stream>>>(vrow, vbT);

    attn_mfma<<<1024, 256, 0, stream>>>(qbp, kbp, vbT, attnb);

    gemm_bt_mfma<0><<<(D_MODEL / 128) * (BT / 128), 256, 0, stream>>>(
        attnb, woutb, out, nullptr, nullptr, BT, D_MODEL, D_MODEL);
}

// Round 10
// 175.595 us; speedup vs baseline: 1.0208x; 1.0208x over previous
//
#include <hip/hip_runtime.h>
#include <hip/hip_bf16.h>

// B=2, T=2048, D=1024, H=16, hd=64
#define T_SEQ 2048
#define D_MODEL 1024
#define BT 4096
#define QKV_N 3072

typedef __attribute__((ext_vector_type(8))) short bf16x8;
typedef __attribute__((ext_vector_type(4))) short bf16x4;
typedef __attribute__((ext_vector_type(4))) float f32x4;

typedef unsigned int __attribute__((address_space(1))) as1_uint;
typedef unsigned int __attribute__((address_space(3))) as3_uint;

__device__ __forceinline__ unsigned short f2bf(float f) {
    unsigned u = __builtin_bit_cast(unsigned, f);
    u += 0x7fffu + ((u >> 16) & 1u);   // round-to-nearest-even
    return (unsigned short)(u >> 16);
}
__device__ __forceinline__ float bf2f(unsigned short h) {
    unsigned u = ((unsigned)h) << 16;
    return __builtin_bit_cast(float, u);
}
__device__ __forceinline__ void gload_lds16(const void* g, void* l) {
    __builtin_amdgcn_global_load_lds((const as1_uint*)g, (as3_uint*)l, 16, 0, 0);
}
__device__ __forceinline__ unsigned cvtpk_bf16(float lo, float hi) {
    unsigned r;
    asm("v_cvt_pk_bf16_f32 %0, %1, %2" : "=v"(r) : "v"(lo), "v"(hi));
    return r;
}

// ---------------- fp32 -> bf16 convert, all three tensors in one launch ------
__global__ __launch_bounds__(256) void cvt_bf16_3(const float* __restrict__ s0, unsigned short* __restrict__ d0, int n0,
                                                  const float* __restrict__ s1, unsigned short* __restrict__ d1, int n1,
                                                  const float* __restrict__ s2, unsigned short* __restrict__ d2, int n2) {
    int i = blockIdx.x * 256 + threadIdx.x;   // 8-element units
    const float* s; unsigned short* d;
    if (i < n0) { s = s0; d = d0; }
    else if (i < n0 + n1) { i -= n0; s = s1; d = d1; }
    else if (i < n0 + n1 + n2) { i -= n0 + n1; s = s2; d = d2; }
    else return;
    const float4* sp = (const float4*)s + (size_t)i * 2;
    const float4 a = sp[0], b = sp[1];
    uint4 o;
    o.x = (unsigned)f2bf(a.x) | ((unsigned)f2bf(a.y) << 16);
    o.y = (unsigned)f2bf(a.z) | ((unsigned)f2bf(a.w) << 16);
    o.z = (unsigned)f2bf(b.x) | ((unsigned)f2bf(b.y) << 16);
    o.w = (unsigned)f2bf(b.z) | ((unsigned)f2bf(b.w) << 16);
    ((uint4*)d)[i] = o;
}

// ---------------- MFMA GEMM: C[M,N] = A[M,K] @ B[N,K]^T (bf16 in, fp32 acc) ----
template<int MODE>
__global__ __launch_bounds__(256) void gemm_bt_mfma(const unsigned short* __restrict__ A,
                                                    const unsigned short* __restrict__ B,
                                                    void* __restrict__ Cout,
                                                    unsigned short* __restrict__ qbp,
                                                    unsigned short* __restrict__ kbp,
                                                    int M, int N, int K) {
    __shared__ unsigned short As[128 * 64];
    __shared__ unsigned short Bs[128 * 64];
    const int tid = threadIdx.x;
    const int w = tid >> 6;
    const int l = tid & 63;
    const int l15 = l & 15, l4 = l >> 4;

    const int nblocks = (M / 128) * (N / 128);
    const int cpx = nblocks >> 3;
    const int id2 = (blockIdx.x & 7) * cpx + (blockIdx.x >> 3);
    const int bm = (id2 & 31) * 128;
    const int bn = (id2 >> 5) * 128;

    const int wm = (w >> 1) * 64, wn = (w & 1) * 64;

    const f32x4 z = {0.f, 0.f, 0.f, 0.f};
    f32x4 acc[4][4];
#pragma unroll
    for (int m = 0; m < 4; ++m)
#pragma unroll
        for (int n = 0; n < 4; ++n) acc[m][n] = z;

    const int lrow = l >> 3;
    const int lslot = (l & 7) ^ (lrow & 7);   // pre-swizzled global source slot

    for (int k0 = 0; k0 < K; k0 += 64) {
#pragma unroll
        for (int i = 0; i < 4; ++i) {
            const int row = w * 32 + i * 8 + lrow;
            gload_lds16(A + (size_t)(bm + row) * K + k0 + lslot * 8, As + (w * 4 + i) * 512);
            gload_lds16(B + (size_t)(bn + row) * K + k0 + lslot * 8, Bs + (w * 4 + i) * 512);
        }
        __syncthreads();
        bf16x8 af[4][2], bfr[4][2];
#pragma unroll
        for (int m = 0; m < 4; ++m) {
            const int row = wm + m * 16 + l15;
            af[m][0] = *(const bf16x8*)(As + row * 64 + ((l4 ^ (row & 7)) * 8));
            af[m][1] = *(const bf16x8*)(As + row * 64 + (((4 + l4) ^ (row & 7)) * 8));
        }
#pragma unroll
        for (int n = 0; n < 4; ++n) {
            const int row = wn + n * 16 + l15;
            bfr[n][0] = *(const bf16x8*)(Bs + row * 64 + ((l4 ^ (row & 7)) * 8));
            bfr[n][1] = *(const bf16x8*)(Bs + row * 64 + (((4 + l4) ^ (row & 7)) * 8));
        }
#pragma unroll
        for (int m = 0; m < 4; ++m)
#pragma unroll
            for (int n = 0; n < 4; ++n) {
                acc[m][n] = __builtin_amdgcn_mfma_f32_16x16x32_bf16(af[m][0], bfr[n][0], acc[m][n], 0, 0, 0);
                acc[m][n] = __builtin_amdgcn_mfma_f32_16x16x32_bf16(af[m][1], bfr[n][1], acc[m][n], 0, 0, 0);
            }
        __syncthreads();
    }

    if (MODE == 0) {
#pragma unroll
        for (int m = 0; m < 4; ++m)
#pragma unroll
            for (int n = 0; n < 4; ++n)
#pragma unroll
                for (int r = 0; r < 4; ++r) {
                    const int row = bm + wm + m * 16 + l4 * 4 + r;
                    const int col = bn + wn + n * 16 + l15;
                    ((float*)Cout)[(size_t)row * N + col] = acc[m][n][r];
                }
    } else {
        // fused QKV epilogue. Wave's 64 cols = exactly one head of q, k or v.
        const int gcol0 = bn + wn;
        const int part = gcol0 >> 10;        // 0=q 1=k 2=v (wave-uniform)
        const int h = (gcol0 >> 6) & 15;
        if (part < 2) {
            unsigned short* dst = part ? kbp : qbp;
#pragma unroll
            for (int m = 0; m < 4; ++m)
#pragma unroll
                for (int r = 0; r < 4; ++r) {
                    float ss = 0.f;
#pragma unroll
                    for (int n = 0; n < 4; ++n) ss = fmaf(acc[m][n][r], acc[m][n][r], ss);
                    ss += __shfl_xor(ss, 1);
                    ss += __shfl_xor(ss, 2);
                    ss += __shfl_xor(ss, 4);
                    ss += __shfl_xor(ss, 8);
                    const float sc = 1.0f / fmaxf(sqrtf(ss), 1e-12f);
                    const int row = bm + wm + m * 16 + l4 * 4 + r;
                    const int bh2 = (row >> 11) * 16 + h;
                    unsigned short* pdst = dst + ((size_t)bh2 * T_SEQ + (row & 2047)) * 64 + l15;
#pragma unroll
                    for (int n = 0; n < 4; ++n) pdst[n * 16] = f2bf(acc[m][n][r] * sc);
                }
        } else {
            unsigned short* vrow = (unsigned short*)Cout;    // [4096][1024]
            const int vcol0 = gcol0 - 2048;
#pragma unroll
            for (int m = 0; m < 4; ++m)
#pragma unroll
                for (int n = 0; n < 4; ++n)
#pragma unroll
                    for (int r = 0; r < 4; ++r) {
                        const int row = bm + wm + m * 16 + l4 * 4 + r;
                        vrow[(size_t)row * D_MODEL + vcol0 + n * 16 + l15] = f2bf(acc[m][n][r]);
                    }
        }
    }
}

// ---------------- V relayout: vrow [b][t][h*64+d] -> vbT [b][h][d][t''] ------
// s' = perm(t&63) = [t5 t3 t2 t4 t1 t0]; slot (s'>>3) ^= (d&7).
__global__ __launch_bounds__(256) void v_cvt_T(const unsigned short* __restrict__ vrow,
                                               unsigned short* __restrict__ vbT) {
    __shared__ unsigned short tile[64][72];  // [d][t]
    const int bh = blockIdx.y;
    const int b = bh >> 4, h = bh & 15;
    const int t0 = blockIdx.x * 64;
    const int r = threadIdx.x >> 2;          // t within tile
    const int c = (threadIdx.x & 3) * 16;    // d chunk
    const unsigned short* src = vrow + (size_t)(b * T_SEQ + t0 + r) * D_MODEL + h * 64 + c;
    uint4 v0 = *(const uint4*)(src);
    uint4 v1 = *(const uint4*)(src + 8);
    unsigned short tmp[16];
    *(uint4*)tmp = v0;
    *(uint4*)(tmp + 8) = v1;
#pragma unroll
    for (int j = 0; j < 16; ++j) tile[c + j][r] = tmp[j];
    __syncthreads();
    const int d = threadIdx.x >> 2;
    const int tc = (threadIdx.x & 3) * 16;   // t chunk base (0,16,32,48)
    const int t5 = tc >> 5, t4 = (tc >> 4) & 1;
    unsigned short* dstrow = vbT + ((size_t)bh * 64 + d) * T_SEQ + t0;
    const int dp = d & 7;
#pragma unroll
    for (int q = 0; q < 4; ++q) {            // j = q*4 + i, i=0..3
        unsigned short tmp2[4];
#pragma unroll
        for (int i = 0; i < 4; ++i) tmp2[i] = tile[d][tc + q * 4 + i];
        const int slot = (t5 * 4 + q) ^ dp;
        *(uint2*)(dstrow + slot * 8 + t4 * 4) = *(uint2*)tmp2;
    }
}

// ---------------- Causal YAT attention: split-KV, MFMA, swapped-QK ----------
// YAT scores are associative sums (no softmax max) -> exact split-KV:
// j<16: one block, kv tiles 0..j, direct write.
// j>=16: two blocks, chunk0 = kv 0..15, chunk1 = kv 16..j; each writes
// bf16 num[64][64] + f32 den[64] partials; attn_reduce combines.
// Max 16 serial steps per block (was 32) + >=5 blocks/CU with backfill.
#define AT_TS 64

// task table, descending step-count (longest dispatched first): packed (j<<1)|chunk
static __device__ const unsigned char task_tab[48] = {
    (15<<1)|0,(16<<1)|0,(17<<1)|0,(18<<1)|0,(19<<1)|0,(20<<1)|0,(21<<1)|0,(22<<1)|0,
    (23<<1)|0,(24<<1)|0,(25<<1)|0,(26<<1)|0,(27<<1)|0,(28<<1)|0,(29<<1)|0,(30<<1)|0,
    (31<<1)|0,(31<<1)|1,
    (14<<1)|0,(30<<1)|1,(13<<1)|0,(29<<1)|1,(12<<1)|0,(28<<1)|1,(11<<1)|0,(27<<1)|1,
    (10<<1)|0,(26<<1)|1,(9<<1)|0,(25<<1)|1,(8<<1)|0,(24<<1)|1,(7<<1)|0,(23<<1)|1,
    (6<<1)|0,(22<<1)|1,(5<<1)|0,(21<<1)|1,(4<<1)|0,(20<<1)|1,(3<<1)|0,(19<<1)|1,
    (2<<1)|0,(18<<1)|1,(1<<1)|0,(17<<1)|1,(0<<1)|0,(16<<1)|1,
};

__global__ __launch_bounds__(256, 4) void attn_mfma(const unsigned short* __restrict__ qb,
                                                    const unsigned short* __restrict__ kb,
                                                    const unsigned short* __restrict__ vbT,
                                                    unsigned short* __restrict__ attnb,
                                                    unsigned short* __restrict__ pnum,
                                                    float* __restrict__ pden) {
    __shared__ unsigned short Ks[2][64 * 64];
    __shared__ unsigned short Vs[2][64 * 64];

    const int tid = threadIdx.x;
    const int w = tid >> 6;
    const int l = tid & 63;
    const int l15 = l & 15, l4 = l >> 4;

    // id = ((task*4 + hl) << 3) | xcd  -> task-major (longest first), XCD spread
    const int id = blockIdx.x;               // 0..1535
    const int xcd = id & 7;
    const int wq = id >> 3;                  // 0..191
    const int hl = wq & 3;
    const int task = wq >> 2;                // 0..47
    const int bh = xcd * 4 + hl;
    const int tv = task_tab[task];
    const int j = tv >> 1;
    const int chunk = tv & 1;
    const int nst = chunk ? (j - 15) : (j < 16 ? j + 1 : 16);
    const bool mfin = chunk ? true : (j < 16);   // final step contains diagonal?
    const int s_base = chunk * 16;               // in kv-tile units
    const int t0 = j * 64;

    const size_t hb = (size_t)bh * T_SEQ * 64;

    // ---- staging pointers ----
    const int lrow = l >> 3;
    const int lslot = (l & 7) ^ (lrow & 7);   // K: bake swizzle at stage
    const unsigned short* kgp[2];
    const unsigned short* vgp[2];
    unsigned short* kdst[2];
    unsigned short* vdst[2];
#pragma unroll
    for (int c = 0; c < 2; ++c) {
        const int row = w * 16 + c * 8 + lrow;
        kgp[c] = kb + hb + (size_t)(s_base * 64 + row) * 64 + lslot * 8;
        vgp[c] = vbT + hb + (size_t)row * T_SEQ + s_base * 64 + (l & 7) * 8;  // V: linear (pre-baked)
        kdst[c] = &Ks[0][(w * 2 + c) * 512];
        vdst[c] = &Vs[0][(w * 2 + c) * 512];
    }

    // ---- hoisted LDS read bases ----
    const int p = l15 & 7;
    const unsigned short* kfp0 = &Ks[0][0] + l15 * 64 + ((l4 ^ p) * 8);
    const unsigned short* kfp1 = &Ks[0][0] + l15 * 64 + (((4 + l4) ^ p) * 8);
    const unsigned short* vfp0 = &Vs[0][0] + l15 * 64 + ((l4 ^ p) * 8);
    const unsigned short* vfp1 = &Vs[0][0] + l15 * 64 + (((4 + l4) ^ p) * 8);

    // Q B-fragment
    bf16x8 qf0, qf1;
    {
        const unsigned short* qp = qb + hb + (size_t)(t0 + w * 16 + l15) * 64 + l4 * 8;
        qf0 = *(const bf16x8*)(qp);
        qf1 = *(const bf16x8*)(qp + 32);
    }

    const f32x4 z = {0.f, 0.f, 0.f, 0.f};
    f32x4 acc[4];
#pragma unroll
    for (int i = 0; i < 4; ++i) acc[i] = z;
    float accd = 0.f;

    const int wrow0 = t0 + w * 16;
    const int tq = wrow0 + l15;

    // prologue: stage tile 0 into buf 0
#pragma unroll
    for (int c = 0; c < 2; ++c) {
        gload_lds16(kgp[c], kdst[c]);
        gload_lds16(vgp[c], vdst[c]);
    }

    auto compute_tile = [&](int roff, int s0, bool mask) {
        const unsigned short* kc0 = kfp0 + roff;
        const unsigned short* kc1 = kfp1 + roff;
        f32x4 sC[4];
        __builtin_amdgcn_s_setprio(1);
#pragma unroll
        for (int sf = 0; sf < 4; ++sf) {
            bf16x8 kf0 = *(const bf16x8*)(kc0 + sf * 1024);
            bf16x8 kf1 = *(const bf16x8*)(kc1 + sf * 1024);
            f32x4 c = z;
            c = __builtin_amdgcn_mfma_f32_16x16x32_bf16(kf0, qf0, c, 0, 0, 0);
            c = __builtin_amdgcn_mfma_f32_16x16x32_bf16(kf1, qf1, c, 0, 0, 0);
            sC[sf] = c;
        }
        __builtin_amdgcn_s_setprio(0);
        float part_ = 0.f;
#pragma unroll
        for (int sf = 0; sf < 4; ++sf)
#pragma unroll
            for (int r = 0; r < 4; ++r) {
                const float xd = sC[sf][r];
                const float den = __builtin_fmaf(-2.0f, xd, 2.01f);
                float Kv = xd * xd * __builtin_amdgcn_rcpf(den);
                if (mask) {
                    const int s = s0 + sf * 16 + l4 * 4 + r;
                    if (s > tq) Kv = 0.f;
                }
                part_ += Kv;
                sC[sf][r] = Kv;
            }
        accd += part_;
        uint4 p0, p1;
        p0.x = cvtpk_bf16(sC[0][0], sC[0][1]);
        p0.y = cvtpk_bf16(sC[0][2], sC[0][3]);
        p0.z = cvtpk_bf16(sC[1][0], sC[1][1]);
        p0.w = cvtpk_bf16(sC[1][2], sC[1][3]);
        p1.x = cvtpk_bf16(sC[2][0], sC[2][1]);
        p1.y = cvtpk_bf16(sC[2][2], sC[2][3]);
        p1.z = cvtpk_bf16(sC[3][0], sC[3][1]);
        p1.w = cvtpk_bf16(sC[3][2], sC[3][3]);
        const bf16x8 a0 = __builtin_bit_cast(bf16x8, p0);
        const bf16x8 a1 = __builtin_bit_cast(bf16x8, p1);
        const unsigned short* vc0 = vfp0 + roff;
        const unsigned short* vc1 = vfp1 + roff;
        __builtin_amdgcn_s_setprio(1);
#pragma unroll
        for (int df = 0; df < 4; ++df) {
            const bf16x8 B0 = *(const bf16x8*)(vc0 + df * 1024);
            const bf16x8 B1 = *(const bf16x8*)(vc1 + df * 1024);
            acc[df] = __builtin_amdgcn_mfma_f32_16x16x32_bf16(a0, B0, acc[df], 0, 0, 0);
            acc[df] = __builtin_amdgcn_mfma_f32_16x16x32_bf16(a1, B1, acc[df], 0, 0, 0);
        }
        __builtin_amdgcn_s_setprio(0);
    };

    // interior steps
    for (int st = 0; st < nst - 1; ++st) {
        const int dsto = ((st & 1) ^ 1) * 4096;
#pragma unroll
        for (int c = 0; c < 2; ++c) {
            kgp[c] += 4096;
            vgp[c] += 64;
            gload_lds16(kgp[c], kdst[c] + dsto);
            gload_lds16(vgp[c], vdst[c] + dsto);
        }
        asm volatile("s_waitcnt vmcnt(4)" ::: "memory");
        __builtin_amdgcn_sched_barrier(0);
        __builtin_amdgcn_s_barrier();
        compute_tile((st & 1) * 4096, (s_base + st) * AT_TS, false);
        __builtin_amdgcn_sched_barrier(0);
        __builtin_amdgcn_s_barrier();
    }
    // final step
    {
        asm volatile("s_waitcnt vmcnt(0)" ::: "memory");
        __builtin_amdgcn_sched_barrier(0);
        __builtin_amdgcn_s_barrier();
        compute_tile(((nst - 1) & 1) * 4096, (s_base + nst - 1) * AT_TS, mfin);
    }

    // denominator: full sum across l4 groups (disjoint s ranges)
    accd += __shfl_xor(accd, 16);
    accd += __shfl_xor(accd, 32);

    if (!chunk && j < 16) {
        // direct write
        const int b = bh >> 4, h = bh & 15;
#pragma unroll
        for (int r = 0; r < 4; ++r) {
            const float den = __shfl(accd, l4 * 4 + r) + 1e-6f;
#pragma unroll
            for (int df = 0; df < 4; ++df) {
                const int t = wrow0 + l4 * 4 + r;
                const float o = acc[df][r] / den;
                attnb[((size_t)b * T_SEQ + t) * D_MODEL + h * 64 + df * 16 + l15] = f2bf(o);
            }
        }
    } else {
        // partial write: num bf16 [64][64], den f32 [64]
        const int pj = j - 16;
        const int pidx = (bh * 16 + pj) * 2 + chunk;
        unsigned short* np = pnum + (size_t)pidx * 4096;
#pragma unroll
        for (int r = 0; r < 4; ++r)
#pragma unroll
            for (int df = 0; df < 4; ++df)
                np[(w * 16 + l4 * 4 + r) * 64 + df * 16 + l15] = f2bf(acc[df][r]);
        if (l4 == 0) pden[pidx * 64 + w * 16 + l15] = accd;
    }
}

// ---------------- combine split-KV partials for j >= 16 ----------------
__global__ __launch_bounds__(256) void attn_reduce(const unsigned short* __restrict__ pnum,
                                                   const float* __restrict__ pden,
                                                   unsigned short* __restrict__ attnb) {
    const int bh = blockIdx.y;          // 0..31
    const int jj = blockIdx.x;          // 0..15 -> j = 16+jj
    const int row = threadIdx.x >> 2;   // 0..63
    const int d0 = (threadIdx.x & 3) * 16;
    const int pi = (bh * 16 + jj) * 2;
    const float den = pden[pi * 64 + row] + pden[(pi + 1) * 64 + row] + 1e-6f;
    const float inv = 1.0f / den;
    const unsigned short* n0 = pnum + (size_t)pi * 4096 + row * 64 + d0;
    const unsigned short* n1 = n0 + 4096;
    const int b = bh >> 4, h = bh & 15;
    unsigned short* dst = attnb + ((size_t)b * T_SEQ + (16 + jj) * 64 + row) * D_MODEL + h * 64 + d0;
    uint4 a0 = *(const uint4*)n0, a1 = *(const uint4*)(n0 + 8);
    uint4 c0 = *(const uint4*)n1, c1 = *(const uint4*)(n1 + 8);
    unsigned short sa[8], sb[8], o[16];
    *(uint4*)sa = a0; *(uint4*)sb = c0;
#pragma unroll
    for (int i = 0; i < 8; ++i) o[i] = f2bf((bf2f(sa[i]) + bf2f(sb[i])) * inv);
    *(uint4*)sa = a1; *(uint4*)sb = c1;
#pragma unroll
    for (int i = 0; i < 8; ++i) o[8 + i] = f2bf((bf2f(sa[i]) + bf2f(sb[i])) * inv);
    *(uint4*)dst = *(uint4*)o;
    *(uint4*)(dst + 8) = *(uint4*)(o + 8);
}

extern "C" void kernel_launch(void* const* d_in, const int* in_sizes, int n_in,
                              void* d_out, int out_size, void* d_ws, size_t ws_size,
                              hipStream_t stream) {
    const float* x    = (const float*)d_in[0];   // [2,2048,1024]
    const float* Wqkv = (const float*)d_in[1];   // [3072,1024]
    const float* Wout = (const float*)d_in[2];   // [1024,1024]
    float* out = (float*)d_out;                  // [2,2048,1024] fp32

    // Workspace overlay (58 MB):
    //  [0,8):    xb   (dead after gemm1 -> reused as pnum)
    //  [8,16):   wqkvb (6 used)
    //  [16,24):  vrow (dead after v_cvt_T -> reused as pden)
    //  [24,32):  vbT
    //  [32,34):  woutb
    //  [34,42):  qb    [42,50): kb    [50,58): attnb
    char* ws = (char*)d_ws;
    unsigned short* xb    = (unsigned short*)(ws);
    unsigned short* wqkvb = (unsigned short*)(ws + (size_t)8 * 1024 * 1024);
    unsigned short* vrow  = (unsigned short*)(ws + (size_t)16 * 1024 * 1024);
    unsigned short* vbT   = (unsigned short*)(ws + (size_t)24 * 1024 * 1024);
    unsigned short* woutb = (unsigned short*)(ws + (size_t)32 * 1024 * 1024);
    unsigned short* qbp   = (unsigned short*)(ws + (size_t)34 * 1024 * 1024);
    unsigned short* kbp   = (unsigned short*)(ws + (size_t)42 * 1024 * 1024);
    unsigned short* attnb = (unsigned short*)(ws + (size_t)50 * 1024 * 1024);
    unsigned short* pnum  = xb;                  // 8 MB: 32*16*2 * 64*64 bf16
    float*          pden  = (float*)vrow;        // 256 KB: 32*16*2 * 64 f32

    cvt_bf16_3<<<4096, 256, 0, stream>>>(x, xb, BT * D_MODEL / 8,
                                         Wqkv, wqkvb, QKV_N * D_MODEL / 8,
                                         Wout, woutb, D_MODEL * D_MODEL / 8);

    gemm_bt_mfma<2><<<(QKV_N / 128) * (BT / 128), 256, 0, stream>>>(
        xb, wqkvb, vrow, qbp, kbp, BT, QKV_N, D_MODEL);

    v_cvt_T<<<dim3(T_SEQ / 64, 32), 256, 0, stream>>>(vrow, vbT);

    attn_mfma<<<1536, 256, 0, stream>>>(qbp, kbp, vbT, attnb, pnum, pden);

    attn_reduce<<<dim3(16, 32), 256, 0, stream>>>(pnum, pden, attnb);

    gemm_bt_mfma<0><<<(D_MODEL / 128) * (BT / 128), 256, 0, stream>>>(
        attnb, woutb, out, nullptr, nullptr, BT, D_MODEL, D_MODEL);
}

// Round 12
// 169.451 us; speedup vs baseline: 1.0579x; 1.0363x over previous
//
#include <hip/hip_runtime.h>
#include <hip/hip_bf16.h>

// B=2, T=2048, D=1024, H=16, hd=64
#define T_SEQ 2048
#define D_MODEL 1024
#define BT 4096
#define QKV_N 3072

typedef __attribute__((ext_vector_type(8))) short bf16x8;
typedef __attribute__((ext_vector_type(4))) short bf16x4;
typedef __attribute__((ext_vector_type(4))) float f32x4;

typedef unsigned int __attribute__((address_space(1))) as1_uint;
typedef unsigned int __attribute__((address_space(3))) as3_uint;

__device__ __forceinline__ unsigned short f2bf(float f) {
    unsigned u = __builtin_bit_cast(unsigned, f);
    u += 0x7fffu + ((u >> 16) & 1u);   // round-to-nearest-even
    return (unsigned short)(u >> 16);
}
__device__ __forceinline__ float bf2f(unsigned short h) {
    unsigned u = ((unsigned)h) << 16;
    return __builtin_bit_cast(float, u);
}
__device__ __forceinline__ void gload_lds16(const void* g, void* l) {
    __builtin_amdgcn_global_load_lds((const as1_uint*)g, (as3_uint*)l, 16, 0, 0);
}
__device__ __forceinline__ unsigned cvtpk_bf16(float lo, float hi) {
    unsigned r;
    asm("v_cvt_pk_bf16_f32 %0, %1, %2" : "=v"(r) : "v"(lo), "v"(hi));
    return r;
}

// ---------------- fp32 -> bf16 convert, all three tensors in one launch ------
__global__ __launch_bounds__(256) void cvt_bf16_3(const float* __restrict__ s0, unsigned short* __restrict__ d0, int n0,
                                                  const float* __restrict__ s1, unsigned short* __restrict__ d1, int n1,
                                                  const float* __restrict__ s2, unsigned short* __restrict__ d2, int n2) {
    int i = blockIdx.x * 256 + threadIdx.x;   // 8-element units
    const float* s; unsigned short* d;
    if (i < n0) { s = s0; d = d0; }
    else if (i < n0 + n1) { i -= n0; s = s1; d = d1; }
    else if (i < n0 + n1 + n2) { i -= n0 + n1; s = s2; d = d2; }
    else return;
    const float4* sp = (const float4*)s + (size_t)i * 2;
    const float4 a = sp[0], b = sp[1];
    uint4 o;
    o.x = (unsigned)f2bf(a.x) | ((unsigned)f2bf(a.y) << 16);
    o.y = (unsigned)f2bf(a.z) | ((unsigned)f2bf(a.w) << 16);
    o.z = (unsigned)f2bf(b.x) | ((unsigned)f2bf(b.y) << 16);
    o.w = (unsigned)f2bf(b.z) | ((unsigned)f2bf(b.w) << 16);
    ((uint4*)d)[i] = o;
}

// ---------------- MFMA GEMM: C[M,N] = A[M,K] @ B[N,K]^T (bf16 in, fp32 acc) ----
// m97 structure: 128x128 tile, BK=64, 4 waves, global_load_lds width 16,
// slot-XOR swizzle keyed on row&7. 1D grid, XCD-chunked decode.
// MODE 0: fp32 C write.
// MODE 2: fused QKV epilogue — q/k waves L2-normalize their head and write
// bf16 to qb/kb [bh][t][64]; v waves write DIRECTLY into vbT's
// permuted+swizzled layout (Cout = vbT), eliminating the v_cvt_T pass.
template<int MODE>
__global__ __launch_bounds__(256) void gemm_bt_mfma(const unsigned short* __restrict__ A,
                                                    const unsigned short* __restrict__ B,
                                                    void* __restrict__ Cout,
                                                    unsigned short* __restrict__ qbp,
                                                    unsigned short* __restrict__ kbp,
                                                    int M, int N, int K) {
    __shared__ unsigned short As[128 * 64];
    __shared__ unsigned short Bs[128 * 64];
    const int tid = threadIdx.x;
    const int w = tid >> 6;
    const int l = tid & 63;
    const int l15 = l & 15, l4 = l >> 4;

    const int nblocks = (M / 128) * (N / 128);
    const int cpx = nblocks >> 3;
    const int id2 = (blockIdx.x & 7) * cpx + (blockIdx.x >> 3);
    const int bm = (id2 & 31) * 128;
    const int bn = (id2 >> 5) * 128;

    const int wm = (w >> 1) * 64, wn = (w & 1) * 64;

    const f32x4 z = {0.f, 0.f, 0.f, 0.f};
    f32x4 acc[4][4];
#pragma unroll
    for (int m = 0; m < 4; ++m)
#pragma unroll
        for (int n = 0; n < 4; ++n) acc[m][n] = z;

    const int lrow = l >> 3;
    const int lslot = (l & 7) ^ (lrow & 7);   // pre-swizzled global source slot

    for (int k0 = 0; k0 < K; k0 += 64) {
#pragma unroll
        for (int i = 0; i < 4; ++i) {
            const int row = w * 32 + i * 8 + lrow;
            gload_lds16(A + (size_t)(bm + row) * K + k0 + lslot * 8, As + (w * 4 + i) * 512);
            gload_lds16(B + (size_t)(bn + row) * K + k0 + lslot * 8, Bs + (w * 4 + i) * 512);
        }
        __syncthreads();
        bf16x8 af[4][2], bfr[4][2];
#pragma unroll
        for (int m = 0; m < 4; ++m) {
            const int row = wm + m * 16 + l15;
            af[m][0] = *(const bf16x8*)(As + row * 64 + ((l4 ^ (row & 7)) * 8));
            af[m][1] = *(const bf16x8*)(As + row * 64 + (((4 + l4) ^ (row & 7)) * 8));
        }
#pragma unroll
        for (int n = 0; n < 4; ++n) {
            const int row = wn + n * 16 + l15;
            bfr[n][0] = *(const bf16x8*)(Bs + row * 64 + ((l4 ^ (row & 7)) * 8));
            bfr[n][1] = *(const bf16x8*)(Bs + row * 64 + (((4 + l4) ^ (row & 7)) * 8));
        }
#pragma unroll
        for (int m = 0; m < 4; ++m)
#pragma unroll
            for (int n = 0; n < 4; ++n) {
                acc[m][n] = __builtin_amdgcn_mfma_f32_16x16x32_bf16(af[m][0], bfr[n][0], acc[m][n], 0, 0, 0);
                acc[m][n] = __builtin_amdgcn_mfma_f32_16x16x32_bf16(af[m][1], bfr[n][1], acc[m][n], 0, 0, 0);
            }
        __syncthreads();
    }

    if (MODE == 0) {
#pragma unroll
        for (int m = 0; m < 4; ++m)
#pragma unroll
            for (int n = 0; n < 4; ++n)
#pragma unroll
                for (int r = 0; r < 4; ++r) {
                    const int row = bm + wm + m * 16 + l4 * 4 + r;
                    const int col = bn + wn + n * 16 + l15;
                    ((float*)Cout)[(size_t)row * N + col] = acc[m][n][r];
                }
    } else {
        const int gcol0 = bn + wn;
        const int part = gcol0 >> 10;        // 0=q 1=k 2=v (wave-uniform)
        if (part < 2) {
            const int h = (gcol0 >> 6) & 15;
            unsigned short* dst = part ? kbp : qbp;
#pragma unroll
            for (int m = 0; m < 4; ++m)
#pragma unroll
                for (int r = 0; r < 4; ++r) {
                    float ss = 0.f;
#pragma unroll
                    for (int n = 0; n < 4; ++n) ss = fmaf(acc[m][n][r], acc[m][n][r], ss);
                    ss += __shfl_xor(ss, 1);
                    ss += __shfl_xor(ss, 2);
                    ss += __shfl_xor(ss, 4);
                    ss += __shfl_xor(ss, 8);
                    const float sc = 1.0f / fmaxf(sqrtf(ss), 1e-12f);
                    const int row = bm + wm + m * 16 + l4 * 4 + r;
                    const int bh2 = (row >> 11) * 16 + h;
                    unsigned short* pdst = dst + ((size_t)bh2 * T_SEQ + (row & 2047)) * 64 + l15;
#pragma unroll
                    for (int n = 0; n < 4; ++n) pdst[n * 16] = f2bf(acc[m][n][r] * sc);
                }
        } else {
            // V^T fused epilogue: write into vbT [bh][d][t''] directly.
            // s = m*16+l4*4+r -> slot = ((m>>1)*4+l4)^(d&7), elem = (m&1)*4+r.
            unsigned short* vbT = (unsigned short*)Cout;
            const int b = (bm + wm) >> 11;
            const int h = ((bn + wn) >> 6) - 32;
            const int bh2 = b * 16 + h;
            const int tbase = (bm + wm) & 2047;
            const int pxor = l15 & 7;
#pragma unroll
            for (int n = 0; n < 4; ++n) {
                unsigned short* dr = vbT + ((size_t)bh2 * 64 + n * 16 + l15) * T_SEQ + tbase;
#pragma unroll
                for (int m = 0; m < 4; ++m) {
                    const int slot = ((m >> 1) * 4 + l4) ^ pxor;
                    uint2 o;
                    o.x = cvtpk_bf16(acc[m][n][0], acc[m][n][1]);
                    o.y = cvtpk_bf16(acc[m][n][2], acc[m][n][3]);
                    *(uint2*)(dr + slot * 8 + (m & 1) * 4) = o;
                }
            }
        }
    }
}

// ---------------- Causal YAT attention: 3-way split-KV, MFMA, swapped-QK -----
// YAT scores are associative sums -> exact split-KV. Chunk bases 0/11/22
// (tile units), max 11 steps per block:
//   j<11: single block, direct write.
//   11<=j<22: chunks c0 (0..10), c1 (11..j).
//   j>=22:    chunks c0 (0..10), c1 (11..21), c2 (22..j).
// Partials: bf16 num[64][64] + f32 den[64]; attn_reduce combines 2-3 chunks.
#define AT_TS 64

// 63 tasks, descending step count (longest dispatched first): (j<<2)|cid
static __device__ const unsigned char task_tab[63] = {
    // nst = 11 (33 tasks)
    (10<<2)|0,
    (11<<2)|0,(12<<2)|0,(13<<2)|0,(14<<2)|0,(15<<2)|0,(16<<2)|0,(17<<2)|0,
    (18<<2)|0,(19<<2)|0,(20<<2)|0,(21<<2)|0,(22<<2)|0,(23<<2)|0,(24<<2)|0,
    (25<<2)|0,(26<<2)|0,(27<<2)|0,(28<<2)|0,(29<<2)|0,(30<<2)|0,(31<<2)|0,
    (21<<2)|1,(22<<2)|1,(23<<2)|1,(24<<2)|1,(25<<2)|1,(26<<2)|1,(27<<2)|1,
    (28<<2)|1,(29<<2)|1,(30<<2)|1,(31<<2)|1,
    // nst = 10 .. 1, 3 each
    (9<<2)|0,(20<<2)|1,(31<<2)|2,
    (8<<2)|0,(19<<2)|1,(30<<2)|2,
    (7<<2)|0,(18<<2)|1,(29<<2)|2,
    (6<<2)|0,(17<<2)|1,(28<<2)|2,
    (5<<2)|0,(16<<2)|1,(27<<2)|2,
    (4<<2)|0,(15<<2)|1,(26<<2)|2,
    (3<<2)|0,(14<<2)|1,(25<<2)|2,
    (2<<2)|0,(13<<2)|1,(24<<2)|2,
    (1<<2)|0,(12<<2)|1,(23<<2)|2,
    (0<<2)|0,(11<<2)|1,(22<<2)|2,
};

__global__ __launch_bounds__(256, 4) void attn_mfma(const unsigned short* __restrict__ qb,
                                                    const unsigned short* __restrict__ kb,
                                                    const unsigned short* __restrict__ vbT,
                                                    unsigned short* __restrict__ attnb,
                                                    unsigned short* __restrict__ pnum,
                                                    float* __restrict__ pden) {
    __shared__ unsigned short Ks[2][64 * 64];
    __shared__ unsigned short Vs[2][64 * 64];

    const int tid = threadIdx.x;
    const int w = tid >> 6;
    const int l = tid & 63;
    const int l15 = l & 15, l4 = l >> 4;

    // id = ((task*4 + hl) << 3) | xcd  -> task-major (longest first), XCD spread
    const int id = blockIdx.x;               // 0..2015
    const int xcd = id & 7;
    const int wq = id >> 3;                  // 0..251
    const int hl = wq & 3;
    const int task = wq >> 2;                // 0..62
    const int bh = xcd * 4 + hl;
    const int tv = task_tab[task];
    const int j = tv >> 2;
    const int cid = tv & 3;
    const int s_base = cid * 11;             // chunk base in kv-tile units
    int nst = (cid == 0) ? (j + 1) : (j - s_base + 1);
    if (nst > 11) nst = 11;
    const bool mfin = (j <= s_base + 10);    // this chunk contains the diagonal
    const int t0 = j * 64;

    const size_t hb = (size_t)bh * T_SEQ * 64;

    // ---- staging pointers ----
    const int lrow = l >> 3;
    const int lslot = (l & 7) ^ (lrow & 7);   // K: bake swizzle at stage
    const unsigned short* kgp[2];
    const unsigned short* vgp[2];
    unsigned short* kdst[2];
    unsigned short* vdst[2];
#pragma unroll
    for (int c = 0; c < 2; ++c) {
        const int row = w * 16 + c * 8 + lrow;
        kgp[c] = kb + hb + (size_t)(s_base * 64 + row) * 64 + lslot * 8;
        vgp[c] = vbT + hb + (size_t)row * T_SEQ + s_base * 64 + (l & 7) * 8;  // V: linear (pre-baked)
        kdst[c] = &Ks[0][(w * 2 + c) * 512];
        vdst[c] = &Vs[0][(w * 2 + c) * 512];
    }

    // ---- hoisted LDS read bases ----
    const int p = l15 & 7;
    const unsigned short* kfp0 = &Ks[0][0] + l15 * 64 + ((l4 ^ p) * 8);
    const unsigned short* kfp1 = &Ks[0][0] + l15 * 64 + (((4 + l4) ^ p) * 8);
    const unsigned short* vfp0 = &Vs[0][0] + l15 * 64 + ((l4 ^ p) * 8);
    const unsigned short* vfp1 = &Vs[0][0] + l15 * 64 + (((4 + l4) ^ p) * 8);

    // Q B-fragment
    bf16x8 qf0, qf1;
    {
        const unsigned short* qp = qb + hb + (size_t)(t0 + w * 16 + l15) * 64 + l4 * 8;
        qf0 = *(const bf16x8*)(qp);
        qf1 = *(const bf16x8*)(qp + 32);
    }

    const f32x4 z = {0.f, 0.f, 0.f, 0.f};
    f32x4 acc[4];
#pragma unroll
    for (int i = 0; i < 4; ++i) acc[i] = z;
    float accd = 0.f;

    const int wrow0 = t0 + w * 16;
    const int tq = wrow0 + l15;

    // prologue: stage tile 0 into buf 0
#pragma unroll
    for (int c = 0; c < 2; ++c) {
        gload_lds16(kgp[c], kdst[c]);
        gload_lds16(vgp[c], vdst[c]);
    }

    auto compute_tile = [&](int roff, int s0, bool mask) {
        const unsigned short* kc0 = kfp0 + roff;
        const unsigned short* kc1 = kfp1 + roff;
        f32x4 sC[4];
        __builtin_amdgcn_s_setprio(1);
#pragma unroll
        for (int sf = 0; sf < 4; ++sf) {
            bf16x8 kf0 = *(const bf16x8*)(kc0 + sf * 1024);
            bf16x8 kf1 = *(const bf16x8*)(kc1 + sf * 1024);
            f32x4 c = z;
            c = __builtin_amdgcn_mfma_f32_16x16x32_bf16(kf0, qf0, c, 0, 0, 0);
            c = __builtin_amdgcn_mfma_f32_16x16x32_bf16(kf1, qf1, c, 0, 0, 0);
            sC[sf] = c;
        }
        __builtin_amdgcn_s_setprio(0);
        float part_ = 0.f;
#pragma unroll
        for (int sf = 0; sf < 4; ++sf)
#pragma unroll
            for (int r = 0; r < 4; ++r) {
                const float xd = sC[sf][r];
                const float den = __builtin_fmaf(-2.0f, xd, 2.01f);
                float Kv = xd * xd * __builtin_amdgcn_rcpf(den);
                if (mask) {
                    const int s = s0 + sf * 16 + l4 * 4 + r;
                    if (s > tq) Kv = 0.f;
                }
                part_ += Kv;
                sC[sf][r] = Kv;
            }
        accd += part_;
        uint4 p0, p1;
        p0.x = cvtpk_bf16(sC[0][0], sC[0][1]);
        p0.y = cvtpk_bf16(sC[0][2], sC[0][3]);
        p0.z = cvtpk_bf16(sC[1][0], sC[1][1]);
        p0.w = cvtpk_bf16(sC[1][2], sC[1][3]);
        p1.x = cvtpk_bf16(sC[2][0], sC[2][1]);
        p1.y = cvtpk_bf16(sC[2][2], sC[2][3]);
        p1.z = cvtpk_bf16(sC[3][0], sC[3][1]);
        p1.w = cvtpk_bf16(sC[3][2], sC[3][3]);
        const bf16x8 a0 = __builtin_bit_cast(bf16x8, p0);
        const bf16x8 a1 = __builtin_bit_cast(bf16x8, p1);
        const unsigned short* vc0 = vfp0 + roff;
        const unsigned short* vc1 = vfp1 + roff;
        __builtin_amdgcn_s_setprio(1);
#pragma unroll
        for (int df = 0; df < 4; ++df) {
            const bf16x8 B0 = *(const bf16x8*)(vc0 + df * 1024);
            const bf16x8 B1 = *(const bf16x8*)(vc1 + df * 1024);
            acc[df] = __builtin_amdgcn_mfma_f32_16x16x32_bf16(a0, B0, acc[df], 0, 0, 0);
            acc[df] = __builtin_amdgcn_mfma_f32_16x16x32_bf16(a1, B1, acc[df], 0, 0, 0);
        }
        __builtin_amdgcn_s_setprio(0);
    };

    // interior steps
    for (int st = 0; st < nst - 1; ++st) {
        const int dsto = ((st & 1) ^ 1) * 4096;
#pragma unroll
        for (int c = 0; c < 2; ++c) {
            kgp[c] += 4096;
            vgp[c] += 64;
            gload_lds16(kgp[c], kdst[c] + dsto);
            gload_lds16(vgp[c], vdst[c] + dsto);
        }
        asm volatile("s_waitcnt vmcnt(4)" ::: "memory");
        __builtin_amdgcn_sched_barrier(0);
        __builtin_amdgcn_s_barrier();
        compute_tile((st & 1) * 4096, (s_base + st) * AT_TS, false);
        __builtin_amdgcn_sched_barrier(0);
        __builtin_amdgcn_s_barrier();
    }
    // final step
    {
        asm volatile("s_waitcnt vmcnt(0)" ::: "memory");
        __builtin_amdgcn_sched_barrier(0);
        __builtin_amdgcn_s_barrier();
        compute_tile(((nst - 1) & 1) * 4096, (s_base + nst - 1) * AT_TS, mfin);
    }

    // denominator: full sum across l4 groups (disjoint s ranges)
    accd += __shfl_xor(accd, 16);
    accd += __shfl_xor(accd, 32);

    if (cid == 0 && j < 11) {
        // direct write
        const int b = bh >> 4, h = bh & 15;
#pragma unroll
        for (int r = 0; r < 4; ++r) {
            const float den = __shfl(accd, l4 * 4 + r) + 1e-6f;
#pragma unroll
            for (int df = 0; df < 4; ++df) {
                const int t = wrow0 + l4 * 4 + r;
                const float o = acc[df][r] / den;
                attnb[((size_t)b * T_SEQ + t) * D_MODEL + h * 64 + df * 16 + l15] = f2bf(o);
            }
        }
    } else {
        // partial write: num bf16 [64][64], den f32 [64]
        const int pidx = (bh * 21 + (j - 11)) * 3 + cid;
        unsigned short* np = pnum + (size_t)pidx * 4096;
#pragma unroll
        for (int r = 0; r < 4; ++r)
#pragma unroll
            for (int df = 0; df < 4; ++df)
                np[(w * 16 + l4 * 4 + r) * 64 + df * 16 + l15] = f2bf(acc[df][r]);
        if (l4 == 0) pden[pidx * 64 + w * 16 + l15] = accd;
    }
}

// ---------------- combine split-KV partials for j >= 11 ----------------
__global__ __launch_bounds__(256) void attn_reduce(const unsigned short* __restrict__ pnum,
                                                   const float* __restrict__ pden,
                                                   unsigned short* __restrict__ attnb) {
    const int bh = blockIdx.y;          // 0..31
    const int jj = blockIdx.x;          // 0..20 -> j = 11+jj
    const int j = 11 + jj;
    const int cnt = (j < 22) ? 2 : 3;
    const int row = threadIdx.x >> 2;   // 0..63
    const int d0 = (threadIdx.x & 3) * 16;
    const int pi = (bh * 21 + jj) * 3;
    float den = pden[pi * 64 + row] + pden[(pi + 1) * 64 + row];
    if (cnt == 3) den += pden[(pi + 2) * 64 + row];
    const float inv = 1.0f / (den + 1e-6f);
    const unsigned short* n0 = pnum + (size_t)pi * 4096 + row * 64 + d0;
    const int b = bh >> 4, h = bh & 15;
    unsigned short* dst = attnb + ((size_t)b * T_SEQ + j * 64 + row) * D_MODEL + h * 64 + d0;
    float sum[16];
    {
        uint4 a0 = *(const uint4*)n0, a1 = *(const uint4*)(n0 + 8);
        unsigned short s[16];
        *(uint4*)s = a0; *(uint4*)(s + 8) = a1;
#pragma unroll
        for (int i = 0; i < 16; ++i) sum[i] = bf2f(s[i]);
    }
    for (int c = 1; c < cnt; ++c) {
        const unsigned short* nc = n0 + (size_t)c * 4096;
        uint4 a0 = *(const uint4*)nc, a1 = *(const uint4*)(nc + 8);
        unsigned short s[16];
        *(uint4*)s = a0; *(uint4*)(s + 8) = a1;
#pragma unroll
        for (int i = 0; i < 16; ++i) sum[i] += bf2f(s[i]);
    }
    unsigned short o[16];
#pragma unroll
    for (int i = 0; i < 16; ++i) o[i] = f2bf(sum[i] * inv);
    *(uint4*)dst = *(uint4*)o;
    *(uint4*)(dst + 8) = *(uint4*)(o + 8);
}

extern "C" void kernel_launch(void* const* d_in, const int* in_sizes, int n_in,
                              void* d_out, int out_size, void* d_ws, size_t ws_size,
                              hipStream_t stream) {
    const float* x    = (const float*)d_in[0];   // [2,2048,1024]
    const float* Wqkv = (const float*)d_in[1];   // [3072,1024]
    const float* Wout = (const float*)d_in[2];   // [1024,1024]
    float* out = (float*)d_out;                  // [2,2048,1024] fp32

    // Workspace overlay (58 MB):
    //  [0,16.5): xb [0,8) + wqkvb [8,16) (both dead after gemm1) -> pnum
    //  [20,20.6): pden (free region)
    //  [24,32):  vbT   [32,34): woutb
    //  [34,42):  qb    [42,50): kb    [50,58): attnb
    char* ws = (char*)d_ws;
    unsigned short* xb    = (unsigned short*)(ws);
    unsigned short* wqkvb = (unsigned short*)(ws + (size_t)8 * 1024 * 1024);
    unsigned short* vbT   = (unsigned short*)(ws + (size_t)24 * 1024 * 1024);
    unsigned short* woutb = (unsigned short*)(ws + (size_t)32 * 1024 * 1024);
    unsigned short* qbp   = (unsigned short*)(ws + (size_t)34 * 1024 * 1024);
    unsigned short* kbp   = (unsigned short*)(ws + (size_t)42 * 1024 * 1024);
    unsigned short* attnb = (unsigned short*)(ws + (size_t)50 * 1024 * 1024);
    unsigned short* pnum  = xb;                                   // 16.5 MB: 32*21*3 * 4096 bf16
    float*          pden  = (float*)(ws + (size_t)20 * 1024 * 1024);  // 516 KB

    cvt_bf16_3<<<4096, 256, 0, stream>>>(x, xb, BT * D_MODEL / 8,
                                         Wqkv, wqkvb, QKV_N * D_MODEL / 8,
                                         Wout, woutb, D_MODEL * D_MODEL / 8);

    // QKV GEMM with fused L2-norm (q,k -> qbp/kbp) and V^T directly into vbT
    gemm_bt_mfma<2><<<(QKV_N / 128) * (BT / 128), 256, 0, stream>>>(
        xb, wqkvb, vbT, qbp, kbp, BT, QKV_N, D_MODEL);

    attn_mfma<<<2016, 256, 0, stream>>>(qbp, kbp, vbT, attnb, pnum, pden);

    attn_reduce<<<dim3(21, 32), 256, 0, stream>>>(pnum, pden, attnb);

    gemm_bt_mfma<0><<<(D_MODEL / 128) * (BT / 128), 256, 0, stream>>>(
        attnb, woutb, out, nullptr, nullptr, BT, D_MODEL, D_MODEL);
}